// Round 19
// baseline (72.462 us; speedup 1.0000x reference)
//
#include <hip/hip_runtime.h>

// Problem constants (match reference)
constexpr int B    = 64;
constexpr int E    = 512;
constexpr int P    = 31;    // patch size
constexpr int S    = 200;   // canvas size
constexpr int HALF = 15;

// Tiling: 16x16 canvas tiles
constexpr int TS     = 16;
constexpr int NTD    = (S + TS - 1) / TS;    // 13 tiles per dim
constexpr int NTILES = NTD * NTD;            // 169 tiles per batch
constexpr int NBINS  = B * NTILES;           // 10816
constexpr int CAP    = 128;                  // bin capacity (mean ~25, tail ~60)

constexpr int THREADS = 256;
constexpr int NW      = THREADS / 64;        // 4 waves
constexpr int NXCD    = 8;

// ---- Binning (R16-verified): one block per batch, LDS counters, no global
// ---- atomics, no memset dispatch (counts fully rewritten every call).
__global__ __launch_bounds__(E)
void imgs4dto3d_bin_kernel(const int* __restrict__ xyz,
                           int*       __restrict__ counts,
                           unsigned*  __restrict__ entries)
{
    __shared__ int cnt[NTILES];

    const int b = blockIdx.x;
    const int e = threadIdx.x;                   // one thread per emitter

    for (int i = e; i < NTILES; i += E) cnt[i] = 0;
    __syncthreads();

    const int x = xyz[(size_t)(b * E + e) * 3 + 0];
    const int y = xyz[(size_t)(b * E + e) * 3 + 1];
    const unsigned pk = (unsigned)e | ((unsigned)x << 9) | ((unsigned)y << 17);

    const int tr_lo = (x - HALF) >> 4, tr_hi = (x + HALF) >> 4;
    const int tc_lo = (y - HALF) >> 4, tc_hi = (y + HALF) >> 4;

    for (int tr = tr_lo; tr <= tr_hi; ++tr) {
        for (int tc = tc_lo; tc <= tc_hi; ++tc) {
            const int t   = tr * NTD + tc;
            const int pos = atomicAdd(&cnt[t], 1);          // LDS atomic
            if (pos < CAP)
                entries[(size_t)(b * NTILES + t) * CAP + pos] = pk;
        }
    }
    __syncthreads();

    for (int i = e; i < NTILES; i += E)
        counts[b * NTILES + i] = cnt[i];
}

__global__ __launch_bounds__(THREADS)        // no min-wave cap: VGPRs feed the MLP
void imgs4dto3d_gather_kernel(const float*    __restrict__ img,
                              const int*      __restrict__ counts,
                              const unsigned* __restrict__ entries,
                              float*          __restrict__ out)
{
    // XCD-locality swizzle (R15-verified): all 169 tiles of a batch land on one
    // XCD so the 2 MB batch slab stays L2-resident. gridDim.x = 10816 = 8*1352.
    const int wgid = blockIdx.x;
    const int xcd  = wgid & (NXCD - 1);
    const int seq  = wgid >> 3;
    const int b    = ((seq / NTILES) << 3) | xcd;
    const int t    = seq % NTILES;

    const int tid  = threadIdx.x;
    const int wid  = tid >> 6;
    const int lane = tid & 63;

    const int tr = t / NTD;
    const int tc = t % NTD;
    const int r0 = tr * TS;
    const int c0 = tc * TS;

    // lane map (R6/R12-verified): col = lane&15, rowg = lane>>4; 4 rows per lane
    const int col  = lane & 15;
    const int rowg = lane >> 4;
    const int c    = c0 + col;

    const int rr = r0 + rowg * 4 + HALF;    // pr0 = rr - x
    const int cc = c + HALF;                // pc  = cc - y

    // this block's bin, split into 4-aligned contiguous chunks across the 4 waves
    const int bin = b * NTILES + t;
    const int n   = min(counts[bin], CAP);
    const int qsz = ((n + NW * 4 - 1) / (NW * 4)) * 4;   // per-wave chunk, multiple of 4
    const int lo  = min(n, wid * qsz);
    const int hi  = min(n, lo + qsz);

    const uint4* lst = reinterpret_cast<const uint4*>(entries + (size_t)bin * CAP);
    constexpr int LASTW = CAP / 4 - 1;

    float a0 = 0.f, a1 = 0.f, a2 = 0.f, a3 = 0.f;
    const float* imgb = img + (size_t)b * E * (P * P);

    // 16 entries per burst: read 4 entry words, decode all, issue all 64
    // predicated loads into staging registers, then accumulate. One vmcnt
    // round per 16 entries -> whole wave chunk is a single burst for n <= 64.
    for (int i = lo; i < hi; i += 16) {
        const int w0 = i >> 2;
        uint4 ew[4];
        ew[0] = lst[w0];                                     // i < hi -> valid
        #pragma unroll
        for (int k = 1; k < 4; ++k)
            ew[k] = (i + 4 * k < hi) ? lst[min(w0 + k, LASTW)] : ew[0];

        float v[16][4];
        #pragma unroll
        for (int g = 0; g < 4; ++g) {
            const unsigned pks[4] = {ew[g].x, ew[g].y, ew[g].z, ew[g].w};
            #pragma unroll
            for (int u = 0; u < 4; ++u) {
                const int  j   = i + 4 * g + u;
                const bool inb = j < hi;                     // wave-uniform
                const unsigned pk = pks[u];
                const int e = (int)(pk & 511u);
                const int x = (int)((pk >> 9) & 255u);
                const int y = (int)(pk >> 17);

                const int pc  = cc - y;                      // patch col (verified math)
                const int pr0 = rr - x;                      // patch row for q=0
                const bool colok = inb && ((unsigned)pc <= 30u);
                const float* bp = imgb + (size_t)e * (P * P) + pr0 * P + pc;
                #pragma unroll
                for (int q = 0; q < 4; ++q) {
                    const bool kq = colok && ((unsigned)(pr0 + q) <= 30u);
                    v[4 * g + u][q] = kq ? bp[P * q] : 0.f;  // exec-masked load
                }
            }
        }
        #pragma unroll
        for (int u = 0; u < 16; ++u) {
            a0 += v[u][0]; a1 += v[u][1]; a2 += v[u][2]; a3 += v[u][3];
        }
    }

    // ---- reduce the 4 waves' partials in LDS (lane-consecutive, conflict-free) ----
    __shared__ float part[NW * THREADS];    // 4 KB
    part[wid * THREADS + 0 * 64 + lane] = a0;
    part[wid * THREADS + 1 * 64 + lane] = a1;
    part[wid * THREADS + 2 * 64 + lane] = a2;
    part[wid * THREADS + 3 * 64 + lane] = a3;
    __syncthreads();

    // thread tid owns pixel p=tid: q = tid>>6, lane' = tid&63
    const int q     = tid >> 6;
    const int lane2 = tid & 63;
    const int row   = r0 + ((lane2 >> 4) << 2) + q;
    const int cst   = c0 + (lane2 & 15);
    const float v = part[0 * THREADS + tid] + part[1 * THREADS + tid] +
                    part[2 * THREADS + tid] + part[3 * THREADS + tid];
    if (row < S && cst < S) {
        out[(size_t)b * (S * S) + row * S + cst] = v;
    }
}

extern "C" void kernel_launch(void* const* d_in, const int* in_sizes, int n_in,
                              void* d_out, int out_size, void* d_ws, size_t ws_size,
                              hipStream_t stream)
{
    const float* img = (const float*)d_in[0];   // [B, E, P, P] fp32
    const int*   xyz = (const int*)d_in[1];     // [B, E, 3] int32
    float*       out = (float*)d_out;           // [B, 1, S, S] fp32

    int*      counts  = (int*)d_ws;
    unsigned* entries = (unsigned*)d_ws + NBINS;

    imgs4dto3d_bin_kernel<<<B, E, 0, stream>>>(xyz, counts, entries);

    imgs4dto3d_gather_kernel<<<NBINS, THREADS, 0, stream>>>(img, counts, entries, out);
}

// Round 20
// 36.240 us; speedup vs baseline: 1.9995x; 1.9995x over previous
//
#include <hip/hip_runtime.h>

// Problem constants (match reference)
constexpr int B    = 64;
constexpr int E    = 512;
constexpr int P    = 31;    // patch size
constexpr int S    = 200;   // canvas size
constexpr int HALF = 15;

// Tiling: 16x16 canvas tiles
constexpr int TS     = 16;
constexpr int NTD    = (S + TS - 1) / TS;    // 13 tiles per dim
constexpr int NTILES = NTD * NTD;            // 169 tiles per batch
constexpr int NBINS  = B * NTILES;           // 10816
constexpr int CAP    = 128;                  // bin capacity (mean ~25, tail ~60)

constexpr int THREADS = 256;
constexpr int NW      = THREADS / 64;        // 4 waves
constexpr int NXCD    = 8;

// ---- Binning (R16/R17-verified, unchanged): one block per batch, LDS counters,
// ---- no global atomics, no memset dispatch.
__global__ __launch_bounds__(E)
void imgs4dto3d_bin_kernel(const int* __restrict__ xyz,
                           int*       __restrict__ counts,
                           unsigned*  __restrict__ entries)
{
    __shared__ int cnt[NTILES];

    const int b = blockIdx.x;
    const int e = threadIdx.x;                   // one thread per emitter

    for (int i = e; i < NTILES; i += E) cnt[i] = 0;
    __syncthreads();

    const int x = xyz[(size_t)(b * E + e) * 3 + 0];
    const int y = xyz[(size_t)(b * E + e) * 3 + 1];
    const unsigned pk = (unsigned)e | ((unsigned)x << 9) | ((unsigned)y << 17);

    const int tr_lo = (x - HALF) >> 4, tr_hi = (x + HALF) >> 4;
    const int tc_lo = (y - HALF) >> 4, tc_hi = (y + HALF) >> 4;

    for (int tr = tr_lo; tr <= tr_hi; ++tr) {
        for (int tc = tc_lo; tc <= tc_hi; ++tc) {
            const int t   = tr * NTD + tc;
            const int pos = atomicAdd(&cnt[t], 1);          // LDS atomic
            if (pos < CAP)
                entries[(size_t)(b * NTILES + t) * CAP + pos] = pk;
        }
    }
    __syncthreads();

    for (int i = e; i < NTILES; i += E)
        counts[b * NTILES + i] = cnt[i];
}

__global__ __launch_bounds__(THREADS)
void imgs4dto3d_gather_kernel(const float*    __restrict__ img,
                              const int*      __restrict__ counts,
                              const unsigned* __restrict__ entries,
                              float*          __restrict__ out)
{
    // XCD-locality swizzle (R15-verified): all 169 tiles of a batch land on one
    // XCD so the 2 MB batch slab stays L2-resident. gridDim.x = 10816 = 8*1352.
    const int wgid = blockIdx.x;
    const int xcd  = wgid & (NXCD - 1);
    const int seq  = wgid >> 3;
    const int b    = ((seq / NTILES) << 3) | xcd;
    const int t    = seq % NTILES;

    const int tid  = threadIdx.x;
    const int wid  = tid >> 6;
    const int lane = tid & 63;

    const int bin = b * NTILES + t;
    const uint4* lst = reinterpret_cast<const uint4*>(entries + (size_t)bin * CAP);

    // ---- one independent burst: count + this wave's first two static entry
    // ---- words (wave w owns entry-groups g == w mod 4; addresses n-independent)
    const int  n_raw = counts[bin];
    const uint4 wa   = lst[wid];            // entries 4w .. 4w+3
    const uint4 wb   = lst[wid + NW];       // entries 4w+16 .. 4w+19   (word < 32, in-bin)

    const int tr = t / NTD;
    const int tc = t % NTD;
    const int r0 = tr * TS;
    const int c0 = tc * TS;

    // lane map (R6/R12-verified): col = lane&15, rowg = lane>>4; 4 rows per lane
    const int col  = lane & 15;
    const int rowg = lane >> 4;
    const int c    = c0 + col;

    const int rr = r0 + rowg * 4 + HALF;    // pr0 = rr - x
    const int cc = c + HALF;                // pc  = cc - y

    const int n = min(n_raw, CAP);

    float a0 = 0.f, a1 = 0.f, a2 = 0.f, a3 = 0.f;
    const float* imgb = img + (size_t)b * E * (P * P);

    // R17/R18-verified inner body: decode 4 entries, issue 16 predicated loads
    // into staging regs, then accumulate. j0 = first entry index of this word.
    auto process4 = [&](uint4 g, int j0) {
        const unsigned pks[4] = {g.x, g.y, g.z, g.w};
        float v[4][4];
        #pragma unroll
        for (int u = 0; u < 4; ++u) {
            const bool inb = (j0 + u) < n;                   // wave-uniform mask
            const unsigned pk = pks[u];
            const int e = (int)(pk & 511u);
            const int x = (int)((pk >> 9) & 255u);
            const int y = (int)(pk >> 17);

            const int pc  = cc - y;                          // patch col (verified math)
            const int pr0 = rr - x;                          // patch row for q=0
            const bool colok = inb && ((unsigned)pc <= 30u);
            const float* bp = imgb + (size_t)e * (P * P) + pr0 * P + pc;
            #pragma unroll
            for (int q = 0; q < 4; ++q) {
                const bool kq = colok && ((unsigned)(pr0 + q) <= 30u);
                v[u][q] = kq ? bp[P * q] : 0.f;              // exec-masked load
            }
        }
        #pragma unroll
        for (int u = 0; u < 4; ++u) {
            a0 += v[u][0]; a1 += v[u][1]; a2 += v[u][2]; a3 += v[u][3];
        }
    };

    // main coverage: groups w and w+4 handle all n <= 32 (4 waves x 8 entries)
    process4(wa, 4 * wid);
    if (4 * wid + 16 < n) process4(wb, 4 * wid + 16);

    // rare tail (n > 32): groups w + 4k, k >= 2; one word per step
    for (int k = 2; 4 * wid + 16 * k < n; ++k) {
        const uint4 g = lst[wid + NW * k];                   // word <= 31, in-bin
        process4(g, 4 * wid + 16 * k);
    }

    // ---- reduce the 4 waves' partials in LDS (lane-consecutive, conflict-free) ----
    __shared__ float part[NW * THREADS];    // 4 KB
    part[wid * THREADS + 0 * 64 + lane] = a0;
    part[wid * THREADS + 1 * 64 + lane] = a1;
    part[wid * THREADS + 2 * 64 + lane] = a2;
    part[wid * THREADS + 3 * 64 + lane] = a3;
    __syncthreads();

    // thread tid owns pixel p=tid: q = tid>>6, lane' = tid&63
    const int q     = tid >> 6;
    const int lane2 = tid & 63;
    const int row   = r0 + ((lane2 >> 4) << 2) + q;
    const int cst   = c0 + (lane2 & 15);
    const float v = part[0 * THREADS + tid] + part[1 * THREADS + tid] +
                    part[2 * THREADS + tid] + part[3 * THREADS + tid];
    if (row < S && cst < S) {
        out[(size_t)b * (S * S) + row * S + cst] = v;
    }
}

extern "C" void kernel_launch(void* const* d_in, const int* in_sizes, int n_in,
                              void* d_out, int out_size, void* d_ws, size_t ws_size,
                              hipStream_t stream)
{
    const float* img = (const float*)d_in[0];   // [B, E, P, P] fp32
    const int*   xyz = (const int*)d_in[1];     // [B, E, 3] int32
    float*       out = (float*)d_out;           // [B, 1, S, S] fp32

    int*      counts  = (int*)d_ws;
    unsigned* entries = (unsigned*)d_ws + NBINS;

    imgs4dto3d_bin_kernel<<<B, E, 0, stream>>>(xyz, counts, entries);

    imgs4dto3d_gather_kernel<<<NBINS, THREADS, 0, stream>>>(img, counts, entries, out);
}